// Round 9
// baseline (74.419 us; speedup 1.0000x reference)
//
#include <hip/hip_runtime.h>

#define N   32
#define NN  1024

// One WAVE (64 lanes) per batch element. Lane (ty,tx) owns a 4x4 cell tile in
// registers (interior of a 6x6 block g). Halo = border of g, fetched from the
// 8 neighboring lanes' registers via __shfl (ds_bpermute crossbar; no LDS, no
// fence, no bank conflicts). Edge lanes mask their missing halo to INF.
//
// R4-R8 post-mortems: kernel time is LATENCY-bound (one wave per CU, nothing
// to overlap with), insensitive to per-sweep instruction count. So R9
// minimizes the per-sweep CRITICAL PATH: ONE exchange + ONE raster per sweep,
// raster direction cycling SE -> NE -> NW -> SW (fast-sweeping schedule).
// Total raster count stays ~constant vs R4 (same direction coverage per
// raster) while per-sweep latency roughly halves.
//
// Termination: RELAX examines all 8 neighbors, so a single raster that starts
// from fresh halos and changes nothing anywhere verifies the Bellman
// inequality at every cell -> fixpoint reached. Raster order is irrelevant to
// this certificate.
//
// Exactness: every assigned value is an fp-fold (((0+w)+w)+...) of a source
// path; monotone-decreasing chaotic iteration from INF converges to the
// unique fixpoint = min-over-paths fold = the reference's Dijkstra distances
// bitwise (absmax=0 across R1/R3-R8 under seven different orderings).
// LDS only in the epilogue (pred/path) with the single-wave
// __threadfence_block pattern (R2 showed the compiler fence is mandatory).
__global__ __launch_bounds__(64, 1) void dijkstra_path_kernel(
    const float* __restrict__ weights, float* __restrict__ out)
{
    const int b    = blockIdx.x;
    const int lane = threadIdx.x & 63;
    const int ty   = lane >> 3;        // tile row 0..7
    const int tx   = lane & 7;         // tile col 0..7
    const int y0   = ty << 2;          // tile origin (global cell coords)
    const int x0   = tx << 2;

    __shared__ int   pred[NN];         // 4 KB
    __shared__ float pathf[NN];        // 4 KB

    const float INF = __builtin_huge_valf();

    // ---- pathf = 0 ----
    #pragma unroll
    for (int k = 0; k < 16; ++k) pathf[lane + k * 64] = 0.0f;

    // ---- weights tile -> registers (float4 rows) ----
    float w[4][4];
    const float* wb = weights + b * NN;
    #pragma unroll
    for (int i = 0; i < 4; ++i) {
        const float4 v = *(const float4*)(wb + (y0 + i) * N + x0);
        w[i][0] = v.x; w[i][1] = v.y; w[i][2] = v.z; w[i][3] = v.w;
    }

    // ---- register state: 6x6 (interior = my 4x4 tile, border = halo) ----
    float g[6][6];
    #pragma unroll
    for (int i = 0; i < 6; ++i)
        #pragma unroll
        for (int j = 0; j < 6; ++j) g[i][j] = INF;
    if (lane == 0) g[1][1] = 0.0f;     // source (0,0)

    const bool hT = (ty > 0), hB = (ty < 7), hL = (tx > 0), hR = (tx < 7);

    // fetch halo from neighbor lanes' registers; mask off-grid edges to INF
#define EXCHANGE()                                                            \
    {                                                                         \
        float tT[4], tB[4], tL[4], tR[4];                                     \
        _Pragma("unroll")                                                     \
        for (int j = 0; j < 4; ++j) tT[j] = __shfl(g[4][1 + j], lane - 8);    \
        _Pragma("unroll")                                                     \
        for (int j = 0; j < 4; ++j) tB[j] = __shfl(g[1][1 + j], lane + 8);    \
        _Pragma("unroll")                                                     \
        for (int i = 0; i < 4; ++i) tL[i] = __shfl(g[1 + i][4], lane - 1);    \
        _Pragma("unroll")                                                     \
        for (int i = 0; i < 4; ++i) tR[i] = __shfl(g[1 + i][1], lane + 1);    \
        const float cTL = __shfl(g[4][4], lane - 9);                          \
        const float cTR = __shfl(g[4][1], lane - 7);                          \
        const float cBL = __shfl(g[1][4], lane + 7);                          \
        const float cBR = __shfl(g[1][1], lane + 9);                          \
        _Pragma("unroll")                                                     \
        for (int j = 0; j < 4; ++j) {                                         \
            g[0][1 + j] = hT ? tT[j] : INF;                                   \
            g[5][1 + j] = hB ? tB[j] : INF;                                   \
        }                                                                     \
        _Pragma("unroll")                                                     \
        for (int i = 0; i < 4; ++i) {                                         \
            g[1 + i][0] = hL ? tL[i] : INF;                                   \
            g[1 + i][5] = hR ? tR[i] : INF;                                   \
        }                                                                     \
        g[0][0] = (hT && hL) ? cTL : INF;                                     \
        g[0][5] = (hT && hR) ? cTR : INF;                                     \
        g[5][0] = (hB && hL) ? cBL : INF;                                     \
        g[5][5] = (hB && hR) ? cBR : INF;                                     \
    }

    // min3-fused 8-neighbor relax (checks ALL 8 neighbors regardless of order)
#define RELAX(i, j)                                                           \
    {                                                                         \
        const float old = g[(i)][(j)];                                        \
        const float a = fminf(fminf(g[(i)-1][(j)-1], g[(i)-1][(j)]),          \
                              g[(i)-1][(j)+1]);                               \
        const float c = fminf(fminf(g[(i)][(j)-1], g[(i)][(j)+1]),            \
                              g[(i)+1][(j)-1]);                               \
        const float e = fminf(g[(i)+1][(j)], g[(i)+1][(j)+1]);                \
        const float m = fminf(fminf(a, c), e);                                \
        const float nv = m + w[(i)-1][(j)-1];                                 \
        changed |= (nv < old);                                                \
        g[(i)][(j)] = fminf(old, nv);                                         \
    }

    // ---- relaxation sweeps: one exchange + one raster, directions cycling ----
    for (int it = 0; it < 768; ++it) {
        bool changed = false;
        EXCHANGE()
        const int d = it & 3;          // wave-uniform scalar branch
        if (d == 0) {                  // SE: i asc, j asc
            #pragma unroll
            for (int i = 1; i <= 4; ++i)
                #pragma unroll
                for (int j = 1; j <= 4; ++j) RELAX(i, j)
        } else if (d == 1) {           // NE: i desc, j asc
            #pragma unroll
            for (int i = 4; i >= 1; --i)
                #pragma unroll
                for (int j = 1; j <= 4; ++j) RELAX(i, j)
        } else if (d == 2) {           // NW: i desc, j desc
            #pragma unroll
            for (int i = 4; i >= 1; --i)
                #pragma unroll
                for (int j = 4; j >= 1; --j) RELAX(i, j)
        } else {                       // SW: i asc, j desc
            #pragma unroll
            for (int i = 1; i <= 4; ++i)
                #pragma unroll
                for (int j = 4; j >= 1; --j) RELAX(i, j)
        }
        if (!__any((int)changed)) break;
    }
#undef RELAX

    // refresh halo once more so pred argmin sees final neighbor values
    EXCHANGE()
#undef EXCHANGE

    // ---- predecessors: argmin over 8 neighbors of fp(dist_u + w_v), DIRS order ----
    const int dy[8] = {-1, 1, 0, 0, -1, -1, 1, 1};
    const int dx[8] = { 0, 0,-1, 1, -1,  1,-1, 1};
    #pragma unroll
    for (int i = 0; i < 4; ++i)
        #pragma unroll
        for (int j = 0; j < 4; ++j) {
            const int yy = y0 + i, xx = x0 + j;
            const int t  = yy * N + xx;
            int p = 0;
            if (t != 0) {
                float best = INF;
                #pragma unroll
                for (int k = 0; k < 8; ++k) {
                    const float u = g[1 + i + dy[k]][1 + j + dx[k]];  // OOB -> INF
                    const float c = u + w[i][j];
                    if (c < best) { best = c; p = (yy + dy[k]) * N + (xx + dx[k]); }
                }
            }
            pred[t] = p;
        }
    __threadfence_block();             // publish pred (compiler fence; wave DS in-order)

    // ---- serial backtrack from (31,31); pred[0]==0 is the fixed point ----
    if (lane == 0) {
        int cur = NN - 1;
        pathf[cur] = 1.0f;
        for (int s = 0; s < NN && cur != 0; ++s) {
            cur = pred[cur];
            pathf[cur] = 1.0f;
        }
    }
    __threadfence_block();             // publish lane 0's path writes

    // ---- write output (float4 rows) ----
    float* ob = out + b * NN;
    #pragma unroll
    for (int i = 0; i < 4; ++i) {
        const int t = (y0 + i) * N + x0;
        const float4 v = *(const float4*)&pathf[t];
        *(float4*)(ob + t) = v;
    }
}

extern "C" void kernel_launch(void* const* d_in, const int* in_sizes, int n_in,
                              void* d_out, int out_size, void* d_ws, size_t ws_size,
                              hipStream_t stream) {
    const float* w = (const float*)d_in[0];
    float* out = (float*)d_out;
    const int b = in_sizes[0] / NN;   // 128
    dijkstra_path_kernel<<<dim3(b), dim3(64), 0, stream>>>(w, out);
}

// Round 10
// 72.511 us; speedup vs baseline: 1.0263x; 1.0263x over previous
//
#include <hip/hip_runtime.h>

#define N   32
#define NN  1024

// One WAVE per batch element; lane (ty,tx) owns a 4x4 tile in registers
// (interior of 6x6 g). Halo via 8 ds_bpermute (vertical) + 12 DPP row_shr/shl
// (horizontal + corners composed on the vertical bpermute results) — DPP runs
// on the VALU pipe, cutting the LDS-pipe serialization that R4-R9 showed is
// the per-exchange latency floor. All DPP row-boundary-invalid lanes have
// tx==0/7 and are INF-masked. One raster per sweep, direction cycling
// SE->NE->NW->SW (R9 schedule — R4..R9 proved schedule choice is neutral).
//
// Termination: RELAX checks all 8 neighbors; a raster from fresh halos with
// zero changes anywhere certifies the Bellman inequality -> fixpoint.
// Exactness: all values are exact fp path-folds; monotone chaotic iteration
// from INF reaches the unique fixpoint = reference Dijkstra bitwise
// (absmax=0 across R1, R3-R9, eight orderings).
//
// Backtrack: pointer-doubling ancestor tables (anc[k][t] = 2^k-th ancestor)
// built in LDS with the single-wave fence pattern (R2 showed the compiler
// fence is mandatory; wave DS ops are HW-in-order). Lane j marks the
// depth-j and depth-(64+j) ancestors of the target; serial guard handles the
// (practically impossible) >127-hop path.

__device__ __forceinline__ float dpp_from_left(float x) {   // value from lane-1
    int r = __builtin_amdgcn_update_dpp(__builtin_bit_cast(int, x),
                                        __builtin_bit_cast(int, x),
                                        0x111 /*row_shr:1*/, 0xF, 0xF, false);
    return __builtin_bit_cast(float, r);
}
__device__ __forceinline__ float dpp_from_right(float x) {  // value from lane+1
    int r = __builtin_amdgcn_update_dpp(__builtin_bit_cast(int, x),
                                        __builtin_bit_cast(int, x),
                                        0x101 /*row_shl:1*/, 0xF, 0xF, false);
    return __builtin_bit_cast(float, r);
}

__global__ __launch_bounds__(64, 1) void dijkstra_path_kernel(
    const float* __restrict__ weights, float* __restrict__ out)
{
    const int b    = blockIdx.x;
    const int lane = threadIdx.x & 63;
    const int ty   = lane >> 3;        // tile row 0..7
    const int tx   = lane & 7;         // tile col 0..7
    const int y0   = ty << 2;
    const int x0   = tx << 2;

    __shared__ int   anc[7][NN];       // anc[0] = pred; anc[k] = 2^k-ancestor (28 KB)
    __shared__ float pathf[NN];        // 4 KB

    const float INF = __builtin_huge_valf();

    // ---- pathf = 0 ----
    #pragma unroll
    for (int k = 0; k < 16; ++k) pathf[lane + k * 64] = 0.0f;

    // ---- weights tile -> registers ----
    float w[4][4];
    const float* wb = weights + b * NN;
    #pragma unroll
    for (int i = 0; i < 4; ++i) {
        const float4 v = *(const float4*)(wb + (y0 + i) * N + x0);
        w[i][0] = v.x; w[i][1] = v.y; w[i][2] = v.z; w[i][3] = v.w;
    }

    // ---- register state ----
    float g[6][6];
    #pragma unroll
    for (int i = 0; i < 6; ++i)
        #pragma unroll
        for (int j = 0; j < 6; ++j) g[i][j] = INF;
    if (lane == 0) g[1][1] = 0.0f;     // source (0,0)

    const bool hT = (ty > 0), hB = (ty < 7), hL = (tx > 0), hR = (tx < 7);

    // halo exchange: 8 bpermute (vertical rows) + 12 DPP (sides, corners)
#define EXCHANGE()                                                            \
    {                                                                         \
        float rT[4], rB[4], rL[4], rR[4];                                     \
        _Pragma("unroll")                                                     \
        for (int j = 0; j < 4; ++j) rT[j] = __shfl(g[4][1 + j], lane - 8);    \
        _Pragma("unroll")                                                     \
        for (int j = 0; j < 4; ++j) rB[j] = __shfl(g[1][1 + j], lane + 8);    \
        _Pragma("unroll")                                                     \
        for (int i = 0; i < 4; ++i) rL[i] = dpp_from_left (g[1 + i][4]);      \
        _Pragma("unroll")                                                     \
        for (int i = 0; i < 4; ++i) rR[i] = dpp_from_right(g[1 + i][1]);      \
        const float cTL = dpp_from_left (rT[3]);  /* lane-9's g[4][4] */      \
        const float cTR = dpp_from_right(rT[0]);  /* lane-7's g[4][1] */      \
        const float cBL = dpp_from_left (rB[3]);  /* lane+7's g[1][4] */      \
        const float cBR = dpp_from_right(rB[0]);  /* lane+9's g[1][1] */      \
        _Pragma("unroll")                                                     \
        for (int j = 0; j < 4; ++j) {                                         \
            g[0][1 + j] = hT ? rT[j] : INF;                                   \
            g[5][1 + j] = hB ? rB[j] : INF;                                   \
        }                                                                     \
        _Pragma("unroll")                                                     \
        for (int i = 0; i < 4; ++i) {                                         \
            g[1 + i][0] = hL ? rL[i] : INF;                                   \
            g[1 + i][5] = hR ? rR[i] : INF;                                   \
        }                                                                     \
        g[0][0] = (hT && hL) ? cTL : INF;                                     \
        g[0][5] = (hT && hR) ? cTR : INF;                                     \
        g[5][0] = (hB && hL) ? cBL : INF;                                     \
        g[5][5] = (hB && hR) ? cBR : INF;                                     \
    }

#define RELAX(i, j)                                                           \
    {                                                                         \
        const float old = g[(i)][(j)];                                        \
        const float a = fminf(fminf(g[(i)-1][(j)-1], g[(i)-1][(j)]),          \
                              g[(i)-1][(j)+1]);                               \
        const float c = fminf(fminf(g[(i)][(j)-1], g[(i)][(j)+1]),            \
                              g[(i)+1][(j)-1]);                               \
        const float e = fminf(g[(i)+1][(j)], g[(i)+1][(j)+1]);                \
        const float m = fminf(fminf(a, c), e);                                \
        const float nv = m + w[(i)-1][(j)-1];                                 \
        changed |= (nv < old);                                                \
        g[(i)][(j)] = fminf(old, nv);                                         \
    }

    // ---- sweeps: one exchange + one raster, directions cycling ----
    for (int it = 0; it < 768; ++it) {
        bool changed = false;
        EXCHANGE()
        const int d = it & 3;
        if (d == 0) {                  // SE
            #pragma unroll
            for (int i = 1; i <= 4; ++i)
                #pragma unroll
                for (int j = 1; j <= 4; ++j) RELAX(i, j)
        } else if (d == 1) {           // NE
            #pragma unroll
            for (int i = 4; i >= 1; --i)
                #pragma unroll
                for (int j = 1; j <= 4; ++j) RELAX(i, j)
        } else if (d == 2) {           // NW
            #pragma unroll
            for (int i = 4; i >= 1; --i)
                #pragma unroll
                for (int j = 4; j >= 1; --j) RELAX(i, j)
        } else {                       // SW
            #pragma unroll
            for (int i = 1; i <= 4; ++i)
                #pragma unroll
                for (int j = 4; j >= 1; --j) RELAX(i, j)
        }
        if (!__any((int)changed)) break;
    }
#undef RELAX

    EXCHANGE()                         // fresh halo for pred argmin
#undef EXCHANGE

    // ---- predecessors (DIRS order) -> anc[0] ----
    const int dy[8] = {-1, 1, 0, 0, -1, -1, 1, 1};
    const int dx[8] = { 0, 0,-1, 1, -1,  1,-1, 1};
    #pragma unroll
    for (int i = 0; i < 4; ++i)
        #pragma unroll
        for (int j = 0; j < 4; ++j) {
            const int yy = y0 + i, xx = x0 + j;
            const int t  = yy * N + xx;
            int p = 0;
            if (t != 0) {
                float best = INF;
                #pragma unroll
                for (int k = 0; k < 8; ++k) {
                    const float u = g[1 + i + dy[k]][1 + j + dx[k]];
                    const float c = u + w[i][j];
                    if (c < best) { best = c; p = (yy + dy[k]) * N + (xx + dx[k]); }
                }
            }
            anc[0][t] = p;
        }
    __threadfence_block();             // publish pred

    // ---- pointer-doubling ancestor tables ----
    #pragma unroll
    for (int k = 1; k < 7; ++k) {
        int v[16];
        #pragma unroll
        for (int c = 0; c < 16; ++c) {
            const int t = lane + c * 64;
            v[c] = anc[k - 1][anc[k - 1][t]];
        }
        __threadfence_block();         // all reads of anc[k-1] done
        #pragma unroll
        for (int c = 0; c < 16; ++c) anc[k][lane + c * 64] = v[c];
        __threadfence_block();         // publish anc[k]
    }

    // ---- parallel backtrack: lane j marks depth-j and depth-(64+j) ancestors ----
    {
        int c = NN - 1;
        #pragma unroll
        for (int k = 5; k >= 0; --k)
            if ((lane >> k) & 1) c = anc[k][c];
        pathf[c] = 1.0f;               // anc^lane(target); chain past source hits 0 = source (on path)

        int c64 = anc[6][NN - 1];
        int c2 = c64;
        #pragma unroll
        for (int k = 5; k >= 0; --k)
            if ((lane >> k) & 1) c2 = anc[k][c2];
        pathf[c2] = 1.0f;              // anc^(64+lane)(target)

        // guard: path deeper than 127 hops (practically impossible) -> serial tail
        if (lane == 0) {
            int c128 = anc[6][c64];
            if (c128 != 0) {
                int cur = c128;
                for (int s = 0; s < NN && cur != 0; ++s) {
                    pathf[cur] = 1.0f;
                    cur = anc[0][cur];
                }
                pathf[0] = 1.0f;
            }
        }
    }
    __threadfence_block();             // publish path marks

    // ---- write output ----
    float* ob = out + b * NN;
    #pragma unroll
    for (int i = 0; i < 4; ++i) {
        const int t = (y0 + i) * N + x0;
        const float4 v = *(const float4*)&pathf[t];
        *(float4*)(ob + t) = v;
    }
}

extern "C" void kernel_launch(void* const* d_in, const int* in_sizes, int n_in,
                              void* d_out, int out_size, void* d_ws, size_t ws_size,
                              hipStream_t stream) {
    const float* w = (const float*)d_in[0];
    float* out = (float*)d_out;
    const int b = in_sizes[0] / NN;   // 128
    dijkstra_path_kernel<<<dim3(b), dim3(64), 0, stream>>>(w, out);
}